// Round 2
// baseline (1334.857 us; speedup 1.0000x reference)
//
#include <hip/hip_runtime.h>

// ---------------------------------------------------------------------------
// 2-layer GCN (PyG GCNConv semantics) on MI355X.
// out = dinv .* segsum(dinv .* (h @ W)) + b per layer, with self-loops.
// R2: wave-per-node float4 gathers (no LDS/barriers in agg), dense gemm2
// with 64-col padded output, hierarchical scan.
// ---------------------------------------------------------------------------

static inline size_t align256(size_t x) { return (x + 255) & ~(size_t)255; }

__global__ void zero_k(int* __restrict__ p, int n) {
  int i = blockIdx.x * blockDim.x + threadIdx.x;
  if (i < n) p[i] = 0;
}

__global__ void count_k(const int* __restrict__ dst, int* __restrict__ counts, int E) {
  int e = blockIdx.x * blockDim.x + threadIdx.x;
  if (e < E) atomicAdd(&counts[dst[e]], 1);
}

// Per-256-chunk exclusive scan; also emits per-block totals and dinv.
__global__ __launch_bounds__(256) void scan1_k(const int* __restrict__ counts,
                                               int* __restrict__ rowoff,
                                               int* __restrict__ blksum,
                                               float* __restrict__ dinv, int n) {
  __shared__ int ws[4];
  int t = threadIdx.x, lane = t & 63, w = t >> 6;
  int idx = blockIdx.x * 256 + t;
  int v = (idx < n) ? counts[idx] : 0;
  if (idx < n) dinv[idx] = rsqrtf((float)(v + 1));  // +1 self-loop
  int incl = v;
#pragma unroll
  for (int off = 1; off < 64; off <<= 1) {
    int u = __shfl_up(incl, off, 64);
    if (lane >= off) incl += u;
  }
  if (lane == 63) ws[w] = incl;
  __syncthreads();
  int woff = 0;
  for (int k = 0; k < w; ++k) woff += ws[k];
  if (idx < n) rowoff[idx] = woff + incl - v;
  if (t == 255) blksum[blockIdx.x] = woff + incl;
}

// Exclusive scan of block totals (nblk <= 512).
__global__ __launch_bounds__(512) void scan2_k(const int* __restrict__ blksum,
                                               int* __restrict__ blkoff, int nblk) {
  __shared__ int ws[8];
  int t = threadIdx.x, lane = t & 63, w = t >> 6;
  int v = (t < nblk) ? blksum[t] : 0;
  int incl = v;
#pragma unroll
  for (int off = 1; off < 64; off <<= 1) {
    int u = __shfl_up(incl, off, 64);
    if (lane >= off) incl += u;
  }
  if (lane == 63) ws[w] = incl;
  __syncthreads();
  int woff = 0;
  for (int k = 0; k < w; ++k) woff += ws[k];
  if (t < nblk) blkoff[t] = woff + incl - v;
}

__global__ __launch_bounds__(256) void scan3_k(int* __restrict__ rowoff,
                                               const int* __restrict__ blkoff, int n) {
  int idx = blockIdx.x * 256 + threadIdx.x;
  if (idx < n) rowoff[idx] += blkoff[blockIdx.x];
}

__global__ void scatter_k(const int* __restrict__ src, const int* __restrict__ dst,
                          const int* __restrict__ row_off, int* __restrict__ cursor,
                          int* __restrict__ col, int E) {
  int e = blockIdx.x * blockDim.x + threadIdx.x;
  if (e < E) {
    int d = dst[e];
    int p = row_off[d] + atomicAdd(&cursor[d], 1);
    col[p] = src[e];
  }
}

// g1 = dinv .* (x @ W1).  64 rows x 128 cols tile, K in 2x64 LDS chunks.
__global__ __launch_bounds__(256) void gemm1_k(const float* __restrict__ x,
                                               const float* __restrict__ W,
                                               const float* __restrict__ dinv,
                                               float* __restrict__ g1, int n) {
  __shared__ float Xs[64][68];
  __shared__ float Ws[64][132];
  int t = threadIdx.x;
  int row0 = blockIdx.x * 64;
  int cg = t & 15, rg = t >> 4;
  int c0 = cg * 8, r0 = rg * 4;

  float acc[4][8];
#pragma unroll
  for (int r = 0; r < 4; ++r)
#pragma unroll
    for (int c = 0; c < 8; ++c) acc[r][c] = 0.f;

  for (int ks = 0; ks < 2; ++ks) {
    __syncthreads();
#pragma unroll
    for (int q = 0; q < 4; ++q) {
      int f = t + q * 256;
      int r = f >> 4, c4 = f & 15;
      int grow = row0 + r;
      float4 v = make_float4(0.f, 0.f, 0.f, 0.f);
      if (grow < n) v = *(const float4*)(x + (size_t)grow * 128 + ks * 64 + c4 * 4);
      *(float4*)&Xs[r][c4 * 4] = v;
    }
#pragma unroll
    for (int q = 0; q < 8; ++q) {
      int f = t + q * 256;
      int k = f >> 5, c4 = f & 31;
      float4 v = *(const float4*)(W + (size_t)(ks * 64 + k) * 128 + c4 * 4);
      *(float4*)&Ws[k][c4 * 4] = v;
    }
    __syncthreads();

#pragma unroll
    for (int k4 = 0; k4 < 16; ++k4) {
      float4 xv0 = *(const float4*)&Xs[r0 + 0][k4 * 4];
      float4 xv1 = *(const float4*)&Xs[r0 + 1][k4 * 4];
      float4 xv2 = *(const float4*)&Xs[r0 + 2][k4 * 4];
      float4 xv3 = *(const float4*)&Xs[r0 + 3][k4 * 4];
#pragma unroll
      for (int kk = 0; kk < 4; ++kk) {
        const float* wrow = &Ws[k4 * 4 + kk][0];
        float4 wa = *(const float4*)(wrow + c0);
        float4 wb = *(const float4*)(wrow + c0 + 4);
        float a0 = kk == 0 ? xv0.x : kk == 1 ? xv0.y : kk == 2 ? xv0.z : xv0.w;
        float a1 = kk == 0 ? xv1.x : kk == 1 ? xv1.y : kk == 2 ? xv1.z : xv1.w;
        float a2 = kk == 0 ? xv2.x : kk == 1 ? xv2.y : kk == 2 ? xv2.z : xv2.w;
        float a3 = kk == 0 ? xv3.x : kk == 1 ? xv3.y : kk == 2 ? xv3.z : xv3.w;
        float as[4] = {a0, a1, a2, a3};
#pragma unroll
        for (int r = 0; r < 4; ++r) {
          acc[r][0] += as[r] * wa.x; acc[r][1] += as[r] * wa.y;
          acc[r][2] += as[r] * wa.z; acc[r][3] += as[r] * wa.w;
          acc[r][4] += as[r] * wb.x; acc[r][5] += as[r] * wb.y;
          acc[r][6] += as[r] * wb.z; acc[r][7] += as[r] * wb.w;
        }
      }
    }
  }

#pragma unroll
  for (int r = 0; r < 4; ++r) {
    int grow = row0 + r0 + r;
    if (grow < n) {
      float s = dinv[grow];
      float4 va = make_float4(acc[r][0] * s, acc[r][1] * s, acc[r][2] * s, acc[r][3] * s);
      float4 vb = make_float4(acc[r][4] * s, acc[r][5] * s, acc[r][6] * s, acc[r][7] * s);
      float* o = g1 + (size_t)grow * 128 + c0;
      *(float4*)o = va;
      *(float4*)(o + 4) = vb;
    }
  }
}

// h1[i] = relu(dinv[i]*(sum_{j} g1[j] + g1[i]) + b1).
// One wave per node: 2 edges x 32 lanes x float4. No LDS, no barriers.
__global__ __launch_bounds__(256) void agg1_k(const float* __restrict__ g1,
                                              const int* __restrict__ col,
                                              const int* __restrict__ rowoff,
                                              const int* __restrict__ counts,
                                              const float* __restrict__ dinv,
                                              const float* __restrict__ b1,
                                              float* __restrict__ h1, int n) {
  int w = threadIdx.x >> 6, lane = threadIdx.x & 63;
  int i = blockIdx.x * 4 + w;
  if (i >= n) return;
  int q = lane >> 5, c4 = lane & 31;
  int start = rowoff[i], cnt = counts[i];

  float4 acc = make_float4(0.f, 0.f, 0.f, 0.f);
  if (q == 0) acc = *(const float4*)(g1 + (size_t)i * 128 + c4 * 4);  // self-loop

#pragma unroll 4
  for (int e = q; e < cnt; e += 2) {
    int j = col[start + e];
    float4 v = *(const float4*)(g1 + (size_t)j * 128 + c4 * 4);
    acc.x += v.x; acc.y += v.y; acc.z += v.z; acc.w += v.w;
  }

  acc.x += __shfl_xor(acc.x, 32, 64);
  acc.y += __shfl_xor(acc.y, 32, 64);
  acc.z += __shfl_xor(acc.z, 32, 64);
  acc.w += __shfl_xor(acc.w, 32, 64);

  if (q == 0) {
    float di = dinv[i];
    float4 bv = *(const float4*)(b1 + c4 * 4);
    float4 h;
    h.x = fmaxf(di * acc.x + bv.x, 0.f);
    h.y = fmaxf(di * acc.y + bv.y, 0.f);
    h.z = fmaxf(di * acc.z + bv.z, 0.f);
    h.w = fmaxf(di * acc.w + bv.w, 0.f);
    *(float4*)(h1 + (size_t)i * 128 + c4 * 4) = h;
  }
}

// g2 = dinv .* (h1 @ W2), output padded to 64 cols (cols 40..63 = 0).
// 64 rows x 64 cols per block, 256 threads, 4x4 register tile, K=128 staged.
__global__ __launch_bounds__(256) void gemm2_k(const float* __restrict__ h1,
                                               const float* __restrict__ W2,
                                               const float* __restrict__ dinv,
                                               float* __restrict__ g2, int n) {
  __shared__ float Xs[64][132];
  __shared__ float Ws[128][68];
  int t = threadIdx.x;
  int row0 = blockIdx.x * 64;
  int cg = t & 15, rg = t >> 4;
  int c0 = cg * 4, r0 = rg * 4;

  // zero W tile (covers pad cols), then stage W2 (128x40)
  for (int idx = t; idx < 128 * 68; idx += 256) ((float*)Ws)[idx] = 0.f;
#pragma unroll
  for (int q = 0; q < 8; ++q) {  // 64x128 X tile = 2048 float4
    int f = t + q * 256;
    int r = f >> 5, c4 = f & 31;
    int grow = row0 + r;
    float4 v = make_float4(0.f, 0.f, 0.f, 0.f);
    if (grow < n) v = *(const float4*)(h1 + (size_t)grow * 128 + c4 * 4);
    *(float4*)&Xs[r][c4 * 4] = v;
  }
  __syncthreads();
#pragma unroll
  for (int q = 0; q < 5; ++q) {  // 128x40 = 1280 float4
    int f = t + q * 256;
    int k = f / 10, c4 = f % 10;
    float4 v = *(const float4*)(W2 + (size_t)k * 40 + c4 * 4);
    *(float4*)&Ws[k][c4 * 4] = v;
  }
  __syncthreads();

  float acc[4][4];
#pragma unroll
  for (int r = 0; r < 4; ++r)
#pragma unroll
    for (int c = 0; c < 4; ++c) acc[r][c] = 0.f;

#pragma unroll
  for (int k4 = 0; k4 < 32; ++k4) {
    float4 xv[4];
#pragma unroll
    for (int r = 0; r < 4; ++r) xv[r] = *(const float4*)&Xs[r0 + r][k4 * 4];
#pragma unroll
    for (int kk = 0; kk < 4; ++kk) {
      float4 wv = *(const float4*)&Ws[k4 * 4 + kk][c0];
#pragma unroll
      for (int r = 0; r < 4; ++r) {
        float a = kk == 0 ? xv[r].x : kk == 1 ? xv[r].y : kk == 2 ? xv[r].z : xv[r].w;
        acc[r][0] += a * wv.x; acc[r][1] += a * wv.y;
        acc[r][2] += a * wv.z; acc[r][3] += a * wv.w;
      }
    }
  }

#pragma unroll
  for (int r = 0; r < 4; ++r) {
    int grow = row0 + r0 + r;
    if (grow < n) {
      float s = dinv[grow];
      float4 v = make_float4(acc[r][0] * s, acc[r][1] * s, acc[r][2] * s, acc[r][3] * s);
      *(float4*)(g2 + (size_t)grow * 64 + c0) = v;
    }
  }
}

// out[i] = dinv[i]*(sum g2[j] + g2[i]) + b2, g2 padded 64 wide.
// One wave per node: 4 edges x 16 lanes x float4.
__global__ __launch_bounds__(256) void agg2_k(const float* __restrict__ g2,
                                              const int* __restrict__ col,
                                              const int* __restrict__ rowoff,
                                              const int* __restrict__ counts,
                                              const float* __restrict__ dinv,
                                              const float* __restrict__ b2,
                                              float* __restrict__ out, int n) {
  int w = threadIdx.x >> 6, lane = threadIdx.x & 63;
  int i = blockIdx.x * 4 + w;
  if (i >= n) return;
  int q = lane >> 4, c4 = lane & 15;
  int start = rowoff[i], cnt = counts[i];

  float4 acc = make_float4(0.f, 0.f, 0.f, 0.f);
  if (q == 0) acc = *(const float4*)(g2 + (size_t)i * 64 + c4 * 4);  // self-loop

#pragma unroll 4
  for (int e = q; e < cnt; e += 4) {
    int j = col[start + e];
    float4 v = *(const float4*)(g2 + (size_t)j * 64 + c4 * 4);
    acc.x += v.x; acc.y += v.y; acc.z += v.z; acc.w += v.w;
  }

#pragma unroll
  for (int m = 16; m <= 32; m <<= 1) {
    acc.x += __shfl_xor(acc.x, m, 64);
    acc.y += __shfl_xor(acc.y, m, 64);
    acc.z += __shfl_xor(acc.z, m, 64);
    acc.w += __shfl_xor(acc.w, m, 64);
  }

  if (lane < 10) {  // cols 0..39
    float di = dinv[i];
    float4 bv = *(const float4*)(b2 + lane * 4);
    float4 o;
    o.x = di * acc.x + bv.x;
    o.y = di * acc.y + bv.y;
    o.z = di * acc.z + bv.z;
    o.w = di * acc.w + bv.w;
    *(float4*)(out + (size_t)i * 40 + lane * 4) = o;
  }
}

extern "C" void kernel_launch(void* const* d_in, const int* in_sizes, int n_in,
                              void* d_out, int out_size, void* d_ws, size_t ws_size,
                              hipStream_t stream) {
  const float* x  = (const float*)d_in[0];
  const int*   ei = (const int*)d_in[1];
  const float* W1 = (const float*)d_in[2];
  const float* b1 = (const float*)d_in[3];
  const float* W2 = (const float*)d_in[4];
  const float* b2 = (const float*)d_in[5];
  float* out = (float*)d_out;

  const int N = in_sizes[0] / 128;
  const int E = in_sizes[1] / 2;
  const int* src = ei;
  const int* dst = ei + E;
  const int nblk = (N + 255) / 256;

  size_t off = 0;
  auto alloc = [&](size_t bytes) {
    char* p = (char*)d_ws + off;
    off = align256(off + bytes);
    return (void*)p;
  };
  int*   counts = (int*)alloc((size_t)2 * N * 4);  // counts + cursor contiguous
  int*   cursor = counts + N;
  int*   rowoff = (int*)alloc((size_t)N * 4);
  float* dinv   = (float*)alloc((size_t)N * 4);
  int*   blksum = (int*)alloc((size_t)nblk * 4);
  int*   blkoff = (int*)alloc((size_t)nblk * 4);
  int*   col    = (int*)alloc((size_t)E * 4);
  float* g1     = (float*)alloc((size_t)N * 128 * 4);  // reused as g2 (N x 64)
  float* h1     = (float*)alloc((size_t)N * 128 * 4);
  float* g2     = g1;  // g1 dead after agg1_k
  if (off > ws_size) return;

  int gE = (E + 255) / 256;
  int gA = (N + 3) / 4;

  zero_k<<<(2 * N + 255) / 256, 256, 0, stream>>>(counts, 2 * N);
  count_k<<<gE, 256, 0, stream>>>(dst, counts, E);
  scan1_k<<<nblk, 256, 0, stream>>>(counts, rowoff, blksum, dinv, N);
  scan2_k<<<1, 512, 0, stream>>>(blksum, blkoff, nblk);
  scan3_k<<<nblk, 256, 0, stream>>>(rowoff, blkoff, N);
  scatter_k<<<gE, 256, 0, stream>>>(src, dst, rowoff, cursor, col, E);
  gemm1_k<<<(N + 63) / 64, 256, 0, stream>>>(x, W1, dinv, g1, N);
  agg1_k<<<gA, 256, 0, stream>>>(g1, col, rowoff, counts, dinv, b1, h1, N);
  gemm2_k<<<(N + 63) / 64, 256, 0, stream>>>(h1, W2, dinv, g2, N);
  agg2_k<<<gA, 256, 0, stream>>>(g2, col, rowoff, counts, dinv, b2, out, N);
}

// Round 3
// 651.372 us; speedup vs baseline: 2.0493x; 2.0493x over previous
//
#include <hip/hip_runtime.h>

// ---------------------------------------------------------------------------
// 2-layer GCN (PyG GCNConv semantics) on MI355X.
// out = dinv .* segsum(dinv .* (h @ W)) + b per layer, with self-loops.
// R3: gemm2 rewritten (2x8 micro-tile, K-chunked, no spills); g1/g2 stored
// bf16 to halve gather traffic (fp32 accumulation, threshold 5.2e-3).
// ---------------------------------------------------------------------------

static inline size_t align256(size_t x) { return (x + 255) & ~(size_t)255; }

__device__ __forceinline__ unsigned bf16pack2(float a, float b) {
  union { float f; unsigned u; } ua, ub;
  ua.f = a; ub.f = b;
  unsigned ra = (ua.u + 0x7fffu + ((ua.u >> 16) & 1u)) >> 16;
  unsigned rb = (ub.u + 0x7fffu + ((ub.u >> 16) & 1u)) >> 16;
  return ra | (rb << 16);
}

__device__ __forceinline__ void acc_bf16x8(float* acc, uint4 v) {
  union { unsigned u; float f; } c;
  c.u = v.x << 16;          acc[0] += c.f;
  c.u = v.x & 0xffff0000u;  acc[1] += c.f;
  c.u = v.y << 16;          acc[2] += c.f;
  c.u = v.y & 0xffff0000u;  acc[3] += c.f;
  c.u = v.z << 16;          acc[4] += c.f;
  c.u = v.z & 0xffff0000u;  acc[5] += c.f;
  c.u = v.w << 16;          acc[6] += c.f;
  c.u = v.w & 0xffff0000u;  acc[7] += c.f;
}

__global__ void zero_k(int* __restrict__ p, int n) {
  int i = blockIdx.x * blockDim.x + threadIdx.x;
  if (i < n) p[i] = 0;
}

__global__ void count_k(const int* __restrict__ dst, int* __restrict__ counts, int E) {
  int e = blockIdx.x * blockDim.x + threadIdx.x;
  if (e < E) atomicAdd(&counts[dst[e]], 1);
}

// Per-256-chunk exclusive scan; also emits per-block totals and dinv.
__global__ __launch_bounds__(256) void scan1_k(const int* __restrict__ counts,
                                               int* __restrict__ rowoff,
                                               int* __restrict__ blksum,
                                               float* __restrict__ dinv, int n) {
  __shared__ int ws[4];
  int t = threadIdx.x, lane = t & 63, w = t >> 6;
  int idx = blockIdx.x * 256 + t;
  int v = (idx < n) ? counts[idx] : 0;
  if (idx < n) dinv[idx] = rsqrtf((float)(v + 1));  // +1 self-loop
  int incl = v;
#pragma unroll
  for (int off = 1; off < 64; off <<= 1) {
    int u = __shfl_up(incl, off, 64);
    if (lane >= off) incl += u;
  }
  if (lane == 63) ws[w] = incl;
  __syncthreads();
  int woff = 0;
  for (int k = 0; k < w; ++k) woff += ws[k];
  if (idx < n) rowoff[idx] = woff + incl - v;
  if (t == 255) blksum[blockIdx.x] = woff + incl;
}

__global__ __launch_bounds__(512) void scan2_k(const int* __restrict__ blksum,
                                               int* __restrict__ blkoff, int nblk) {
  __shared__ int ws[8];
  int t = threadIdx.x, lane = t & 63, w = t >> 6;
  int v = (t < nblk) ? blksum[t] : 0;
  int incl = v;
#pragma unroll
  for (int off = 1; off < 64; off <<= 1) {
    int u = __shfl_up(incl, off, 64);
    if (lane >= off) incl += u;
  }
  if (lane == 63) ws[w] = incl;
  __syncthreads();
  int woff = 0;
  for (int k = 0; k < w; ++k) woff += ws[k];
  if (t < nblk) blkoff[t] = woff + incl - v;
}

__global__ __launch_bounds__(256) void scan3_k(int* __restrict__ rowoff,
                                               const int* __restrict__ blkoff, int n) {
  int idx = blockIdx.x * 256 + threadIdx.x;
  if (idx < n) rowoff[idx] += blkoff[blockIdx.x];
}

__global__ void scatter_k(const int* __restrict__ src, const int* __restrict__ dst,
                          const int* __restrict__ row_off, int* __restrict__ cursor,
                          int* __restrict__ col, int E) {
  int e = blockIdx.x * blockDim.x + threadIdx.x;
  if (e < E) {
    int d = dst[e];
    int p = row_off[d] + atomicAdd(&cursor[d], 1);
    col[p] = src[e];
  }
}

// g1 = bf16( dinv .* (x @ W1) ).  64 rows x 128 cols tile, K in 2x64 chunks.
__global__ __launch_bounds__(256) void gemm1_k(const float* __restrict__ x,
                                               const float* __restrict__ W,
                                               const float* __restrict__ dinv,
                                               unsigned* __restrict__ g1, int n) {
  __shared__ float Xs[64][68];
  __shared__ float Ws[64][132];
  int t = threadIdx.x;
  int row0 = blockIdx.x * 64;
  int cg = t & 15, rg = t >> 4;
  int c0 = cg * 8, r0 = rg * 4;

  float acc[4][8];
#pragma unroll
  for (int r = 0; r < 4; ++r)
#pragma unroll
    for (int c = 0; c < 8; ++c) acc[r][c] = 0.f;

  for (int ks = 0; ks < 2; ++ks) {
    __syncthreads();
#pragma unroll
    for (int q = 0; q < 4; ++q) {
      int f = t + q * 256;
      int r = f >> 4, c4 = f & 15;
      int grow = row0 + r;
      float4 v = make_float4(0.f, 0.f, 0.f, 0.f);
      if (grow < n) v = *(const float4*)(x + (size_t)grow * 128 + ks * 64 + c4 * 4);
      *(float4*)&Xs[r][c4 * 4] = v;
    }
#pragma unroll
    for (int q = 0; q < 8; ++q) {
      int f = t + q * 256;
      int k = f >> 5, c4 = f & 31;
      float4 v = *(const float4*)(W + (size_t)(ks * 64 + k) * 128 + c4 * 4);
      *(float4*)&Ws[k][c4 * 4] = v;
    }
    __syncthreads();

#pragma unroll
    for (int k4 = 0; k4 < 16; ++k4) {
      float4 xv0 = *(const float4*)&Xs[r0 + 0][k4 * 4];
      float4 xv1 = *(const float4*)&Xs[r0 + 1][k4 * 4];
      float4 xv2 = *(const float4*)&Xs[r0 + 2][k4 * 4];
      float4 xv3 = *(const float4*)&Xs[r0 + 3][k4 * 4];
#pragma unroll
      for (int kk = 0; kk < 4; ++kk) {
        const float* wrow = &Ws[k4 * 4 + kk][0];
        float4 wa = *(const float4*)(wrow + c0);
        float4 wb = *(const float4*)(wrow + c0 + 4);
        float a0 = kk == 0 ? xv0.x : kk == 1 ? xv0.y : kk == 2 ? xv0.z : xv0.w;
        float a1 = kk == 0 ? xv1.x : kk == 1 ? xv1.y : kk == 2 ? xv1.z : xv1.w;
        float a2 = kk == 0 ? xv2.x : kk == 1 ? xv2.y : kk == 2 ? xv2.z : xv2.w;
        float a3 = kk == 0 ? xv3.x : kk == 1 ? xv3.y : kk == 2 ? xv3.z : xv3.w;
        float as[4] = {a0, a1, a2, a3};
#pragma unroll
        for (int r = 0; r < 4; ++r) {
          acc[r][0] += as[r] * wa.x; acc[r][1] += as[r] * wa.y;
          acc[r][2] += as[r] * wa.z; acc[r][3] += as[r] * wa.w;
          acc[r][4] += as[r] * wb.x; acc[r][5] += as[r] * wb.y;
          acc[r][6] += as[r] * wb.z; acc[r][7] += as[r] * wb.w;
        }
      }
    }
  }

#pragma unroll
  for (int r = 0; r < 4; ++r) {
    int grow = row0 + r0 + r;
    if (grow < n) {
      float s = dinv[grow];
      uint4 pv;
      pv.x = bf16pack2(acc[r][0] * s, acc[r][1] * s);
      pv.y = bf16pack2(acc[r][2] * s, acc[r][3] * s);
      pv.z = bf16pack2(acc[r][4] * s, acc[r][5] * s);
      pv.w = bf16pack2(acc[r][6] * s, acc[r][7] * s);
      ((uint4*)g1)[(size_t)grow * 16 + cg] = pv;
    }
  }
}

// h1[i] = relu(dinv[i]*(sum_j g1[j] + g1[i]) + b1).  g1 is bf16 (128/row).
// One wave per node: 4 edge-parities x 16 lanes x 16B (8 bf16 ch each).
__global__ __launch_bounds__(256) void agg1_k(const unsigned* __restrict__ g1,
                                              const int* __restrict__ col,
                                              const int* __restrict__ rowoff,
                                              const int* __restrict__ counts,
                                              const float* __restrict__ dinv,
                                              const float* __restrict__ b1,
                                              float* __restrict__ h1, int n) {
  int w = threadIdx.x >> 6, lane = threadIdx.x & 63;
  int i = blockIdx.x * 4 + w;
  if (i >= n) return;
  int q = lane >> 4, c8 = lane & 15;  // channels c8*8 .. c8*8+7
  const uint4* g1v = (const uint4*)g1;  // 16 uint4 per row
  int start = rowoff[i], cnt = counts[i];

  float acc[8] = {0.f, 0.f, 0.f, 0.f, 0.f, 0.f, 0.f, 0.f};
  if (q == 0) acc_bf16x8(acc, g1v[(size_t)i * 16 + c8]);  // self-loop

#pragma unroll 4
  for (int e = q; e < cnt; e += 4) {
    int j = col[start + e];
    acc_bf16x8(acc, g1v[(size_t)j * 16 + c8]);
  }

#pragma unroll
  for (int k = 0; k < 8; ++k) {
    acc[k] += __shfl_xor(acc[k], 16, 64);
    acc[k] += __shfl_xor(acc[k], 32, 64);
  }

  if (q == 0) {
    float di = dinv[i];
    float4 ba = *(const float4*)(b1 + c8 * 8);
    float4 bb = *(const float4*)(b1 + c8 * 8 + 4);
    float4 o0, o1;
    o0.x = fmaxf(di * acc[0] + ba.x, 0.f);
    o0.y = fmaxf(di * acc[1] + ba.y, 0.f);
    o0.z = fmaxf(di * acc[2] + ba.z, 0.f);
    o0.w = fmaxf(di * acc[3] + ba.w, 0.f);
    o1.x = fmaxf(di * acc[4] + bb.x, 0.f);
    o1.y = fmaxf(di * acc[5] + bb.y, 0.f);
    o1.z = fmaxf(di * acc[6] + bb.z, 0.f);
    o1.w = fmaxf(di * acc[7] + bb.w, 0.f);
    float* o = h1 + (size_t)i * 128 + c8 * 8;
    *(float4*)o = o0;
    *(float4*)(o + 4) = o1;
  }
}

// g2 = bf16( dinv .* (h1 @ W2) ), padded to 64 cols (40..63 = 0).
// 64 rows x 64 cols per block, 256 threads, 2x8 micro-tile, K in 2x64 chunks.
__global__ __launch_bounds__(256) void gemm2_k(const float* __restrict__ h1,
                                               const float* __restrict__ W2,
                                               const float* __restrict__ dinv,
                                               unsigned* __restrict__ g2, int n) {
  __shared__ float Xs[64][68];
  __shared__ float Ws[64][68];
  int t = threadIdx.x;
  int row0 = blockIdx.x * 64;
  int cg = t & 7, rg = t >> 3;
  int c0 = cg * 8, r0 = rg * 2;

  float acc[2][8];
#pragma unroll
  for (int r = 0; r < 2; ++r)
#pragma unroll
    for (int c = 0; c < 8; ++c) acc[r][c] = 0.f;

  // zero W tile once (covers pad cols 40..67; staging only writes cols <40)
  for (int idx = t; idx < 64 * 68; idx += 256) ((float*)Ws)[idx] = 0.f;

  for (int ks = 0; ks < 2; ++ks) {
    __syncthreads();
#pragma unroll
    for (int q = 0; q < 4; ++q) {  // X chunk: 64 rows x 64 k
      int f = t + q * 256;
      int r = f >> 4, c4 = f & 15;
      int grow = row0 + r;
      float4 v = make_float4(0.f, 0.f, 0.f, 0.f);
      if (grow < n) v = *(const float4*)(h1 + (size_t)grow * 128 + ks * 64 + c4 * 4);
      *(float4*)&Xs[r][c4 * 4] = v;
    }
#pragma unroll
    for (int q = 0; q < 3; ++q) {  // W2 chunk: 64 k x 40 cols = 640 float4
      int f = t + q * 256;
      if (f < 640) {
        int k = f / 10, c4 = f % 10;
        float4 v = *(const float4*)(W2 + (size_t)(ks * 64 + k) * 40 + c4 * 4);
        *(float4*)&Ws[k][c4 * 4] = v;
      }
    }
    __syncthreads();

#pragma unroll
    for (int k4 = 0; k4 < 16; ++k4) {
      float4 x0 = *(const float4*)&Xs[r0 + 0][k4 * 4];
      float4 x1 = *(const float4*)&Xs[r0 + 1][k4 * 4];
#pragma unroll
      for (int kk = 0; kk < 4; ++kk) {
        const float* wrow = &Ws[k4 * 4 + kk][0];
        float4 wa = *(const float4*)(wrow + c0);
        float4 wb = *(const float4*)(wrow + c0 + 4);
        float a0 = kk == 0 ? x0.x : kk == 1 ? x0.y : kk == 2 ? x0.z : x0.w;
        float a1 = kk == 0 ? x1.x : kk == 1 ? x1.y : kk == 2 ? x1.z : x1.w;
        acc[0][0] += a0 * wa.x; acc[0][1] += a0 * wa.y;
        acc[0][2] += a0 * wa.z; acc[0][3] += a0 * wa.w;
        acc[0][4] += a0 * wb.x; acc[0][5] += a0 * wb.y;
        acc[0][6] += a0 * wb.z; acc[0][7] += a0 * wb.w;
        acc[1][0] += a1 * wa.x; acc[1][1] += a1 * wa.y;
        acc[1][2] += a1 * wa.z; acc[1][3] += a1 * wa.w;
        acc[1][4] += a1 * wb.x; acc[1][5] += a1 * wb.y;
        acc[1][6] += a1 * wb.z; acc[1][7] += a1 * wb.w;
      }
    }
  }

#pragma unroll
  for (int r = 0; r < 2; ++r) {
    int grow = row0 + r0 + r;
    if (grow < n) {
      float s = dinv[grow];
      uint4 pv;
      pv.x = bf16pack2(acc[r][0] * s, acc[r][1] * s);
      pv.y = bf16pack2(acc[r][2] * s, acc[r][3] * s);
      pv.z = bf16pack2(acc[r][4] * s, acc[r][5] * s);
      pv.w = bf16pack2(acc[r][6] * s, acc[r][7] * s);
      ((uint4*)g2)[(size_t)grow * 8 + cg] = pv;
    }
  }
}

// out[i] = dinv[i]*(sum_j g2[j] + g2[i]) + b2.  g2 bf16, 64 ch padded.
// One wave per node: 8 edge-parities x 8 lanes x 16B (8 bf16 ch each).
__global__ __launch_bounds__(256) void agg2_k(const unsigned* __restrict__ g2,
                                              const int* __restrict__ col,
                                              const int* __restrict__ rowoff,
                                              const int* __restrict__ counts,
                                              const float* __restrict__ dinv,
                                              const float* __restrict__ b2,
                                              float* __restrict__ out, int n) {
  int w = threadIdx.x >> 6, lane = threadIdx.x & 63;
  int i = blockIdx.x * 4 + w;
  if (i >= n) return;
  int q = lane >> 3, c8 = lane & 7;  // channels c8*8 .. c8*8+7
  const uint4* g2v = (const uint4*)g2;  // 8 uint4 per row
  int start = rowoff[i], cnt = counts[i];

  float acc[8] = {0.f, 0.f, 0.f, 0.f, 0.f, 0.f, 0.f, 0.f};
  if (q == 0) acc_bf16x8(acc, g2v[(size_t)i * 8 + c8]);  // self-loop

#pragma unroll 4
  for (int e = q; e < cnt; e += 8) {
    int j = col[start + e];
    acc_bf16x8(acc, g2v[(size_t)j * 8 + c8]);
  }

#pragma unroll
  for (int k = 0; k < 8; ++k) {
    acc[k] += __shfl_xor(acc[k], 8, 64);
    acc[k] += __shfl_xor(acc[k], 16, 64);
    acc[k] += __shfl_xor(acc[k], 32, 64);
  }

  if (lane < 5) {  // cols lane*8 .. lane*8+7 (covers 0..39)
    float di = dinv[i];
    float4 ba = *(const float4*)(b2 + lane * 8);
    float4 bb = *(const float4*)(b2 + lane * 8 + 4);
    float4 o0, o1;
    o0.x = di * acc[0] + ba.x;
    o0.y = di * acc[1] + ba.y;
    o0.z = di * acc[2] + ba.z;
    o0.w = di * acc[3] + ba.w;
    o1.x = di * acc[4] + bb.x;
    o1.y = di * acc[5] + bb.y;
    o1.z = di * acc[6] + bb.z;
    o1.w = di * acc[7] + bb.w;
    float* o = out + (size_t)i * 40 + lane * 8;
    *(float4*)o = o0;
    *(float4*)(o + 4) = o1;
  }
}

extern "C" void kernel_launch(void* const* d_in, const int* in_sizes, int n_in,
                              void* d_out, int out_size, void* d_ws, size_t ws_size,
                              hipStream_t stream) {
  const float* x  = (const float*)d_in[0];
  const int*   ei = (const int*)d_in[1];
  const float* W1 = (const float*)d_in[2];
  const float* b1 = (const float*)d_in[3];
  const float* W2 = (const float*)d_in[4];
  const float* b2 = (const float*)d_in[5];
  float* out = (float*)d_out;

  const int N = in_sizes[0] / 128;
  const int E = in_sizes[1] / 2;
  const int* src = ei;
  const int* dst = ei + E;
  const int nblk = (N + 255) / 256;

  size_t off = 0;
  auto alloc = [&](size_t bytes) {
    char* p = (char*)d_ws + off;
    off = align256(off + bytes);
    return (void*)p;
  };
  int*      counts = (int*)alloc((size_t)2 * N * 4);  // counts + cursor
  int*      cursor = counts + N;
  int*      rowoff = (int*)alloc((size_t)N * 4);
  float*    dinv   = (float*)alloc((size_t)N * 4);
  int*      blksum = (int*)alloc((size_t)nblk * 4);
  int*      blkoff = (int*)alloc((size_t)nblk * 4);
  int*      col    = (int*)alloc((size_t)E * 4);
  unsigned* g1     = (unsigned*)alloc((size_t)N * 128 * 2);  // bf16, reused as g2
  float*    h1     = (float*)alloc((size_t)N * 128 * 4);
  unsigned* g2     = g1;  // bf16 N x 64; g1 dead after agg1_k
  if (off > ws_size) return;

  int gE = (E + 255) / 256;
  int gA = (N + 3) / 4;

  zero_k<<<(2 * N + 255) / 256, 256, 0, stream>>>(counts, 2 * N);
  count_k<<<gE, 256, 0, stream>>>(dst, counts, E);
  scan1_k<<<nblk, 256, 0, stream>>>(counts, rowoff, blksum, dinv, N);
  scan2_k<<<1, 512, 0, stream>>>(blksum, blkoff, nblk);
  scan3_k<<<nblk, 256, 0, stream>>>(rowoff, blkoff, N);
  scatter_k<<<gE, 256, 0, stream>>>(src, dst, rowoff, cursor, col, E);
  gemm1_k<<<(N + 63) / 64, 256, 0, stream>>>(x, W1, dinv, g1, N);
  agg1_k<<<gA, 256, 0, stream>>>(g1, col, rowoff, counts, dinv, b1, h1, N);
  gemm2_k<<<(N + 63) / 64, 256, 0, stream>>>(h1, W2, dinv, g2, N);
  agg2_k<<<gA, 256, 0, stream>>>(g2, col, rowoff, counts, dinv, b2, out, N);
}

// Round 4
// 608.390 us; speedup vs baseline: 2.1941x; 1.0706x over previous
//
#include <hip/hip_runtime.h>

// ---------------------------------------------------------------------------
// 2-layer GCN (PyG GCNConv semantics) on MI355X.
// out = dinv .* segsum(dinv .* (h @ W)) + b per layer, with self-loops.
// R4: CSR build via two-level binning (bucket = dst>>8); kills the 15x
// write amplification of the old per-edge random scatter. g1/g2 bf16.
// ---------------------------------------------------------------------------

static inline size_t align256(size_t x) { return (x + 255) & ~(size_t)255; }

#define BIN_CHUNK 16384
#define MAX_NB 512  // buckets = ceil(N/256); N=100000 -> 391

__device__ __forceinline__ unsigned bf16pack2(float a, float b) {
  union { float f; unsigned u; } ua, ub;
  ua.f = a; ub.f = b;
  unsigned ra = (ua.u + 0x7fffu + ((ua.u >> 16) & 1u)) >> 16;
  unsigned rb = (ub.u + 0x7fffu + ((ub.u >> 16) & 1u)) >> 16;
  return ra | (rb << 16);
}

__device__ __forceinline__ void acc_bf16x8(float* acc, uint4 v) {
  union { unsigned u; float f; } c;
  c.u = v.x << 16;          acc[0] += c.f;
  c.u = v.x & 0xffff0000u;  acc[1] += c.f;
  c.u = v.y << 16;          acc[2] += c.f;
  c.u = v.y & 0xffff0000u;  acc[3] += c.f;
  c.u = v.z << 16;          acc[4] += c.f;
  c.u = v.z & 0xffff0000u;  acc[5] += c.f;
  c.u = v.w << 16;          acc[6] += c.f;
  c.u = v.w & 0xffff0000u;  acc[7] += c.f;
}

__global__ void zero_k(int* __restrict__ p, int n) {
  int i = blockIdx.x * blockDim.x + threadIdx.x;
  if (i < n) p[i] = 0;
}

__global__ void count_k(const int* __restrict__ dst, int* __restrict__ counts, int E) {
  int e = blockIdx.x * blockDim.x + threadIdx.x;
  if (e < E) atomicAdd(&counts[dst[e]], 1);
}

// Per-256-chunk exclusive scan; also emits per-block totals and dinv.
__global__ __launch_bounds__(256) void scan1_k(const int* __restrict__ counts,
                                               int* __restrict__ rowoff,
                                               int* __restrict__ blksum,
                                               float* __restrict__ dinv, int n) {
  __shared__ int ws[4];
  int t = threadIdx.x, lane = t & 63, w = t >> 6;
  int idx = blockIdx.x * 256 + t;
  int v = (idx < n) ? counts[idx] : 0;
  if (idx < n) dinv[idx] = rsqrtf((float)(v + 1));  // +1 self-loop
  int incl = v;
#pragma unroll
  for (int off = 1; off < 64; off <<= 1) {
    int u = __shfl_up(incl, off, 64);
    if (lane >= off) incl += u;
  }
  if (lane == 63) ws[w] = incl;
  __syncthreads();
  int woff = 0;
  for (int k = 0; k < w; ++k) woff += ws[k];
  if (idx < n) rowoff[idx] = woff + incl - v;
  if (t == 255) blksum[blockIdx.x] = woff + incl;
}

__global__ __launch_bounds__(512) void scan2_k(const int* __restrict__ blksum,
                                               int* __restrict__ blkoff, int nblk) {
  __shared__ int ws[8];
  int t = threadIdx.x, lane = t & 63, w = t >> 6;
  int v = (t < nblk) ? blksum[t] : 0;
  int incl = v;
#pragma unroll
  for (int off = 1; off < 64; off <<= 1) {
    int u = __shfl_up(incl, off, 64);
    if (lane >= off) incl += u;
  }
  if (lane == 63) ws[w] = incl;
  __syncthreads();
  int woff = 0;
  for (int k = 0; k < w; ++k) woff += ws[k];
  if (t < nblk) blkoff[t] = woff + incl - v;
}

// Finalize rowoff; emit bucket cursor start (= rowoff[256*b]) per bucket.
__global__ __launch_bounds__(256) void scan3_k(int* __restrict__ rowoff,
                                               const int* __restrict__ blkoff,
                                               int* __restrict__ bucket_cur, int n) {
  int idx = blockIdx.x * 256 + threadIdx.x;
  if (idx < n) {
    int v = rowoff[idx] + blkoff[blockIdx.x];
    rowoff[idx] = v;
    if (threadIdx.x == 0) bucket_cur[blockIdx.x] = v;
  }
}

// Pass 1 of binning: each block takes BIN_CHUNK edges, histograms buckets in
// LDS, reserves one contiguous segment per bucket (1 global atomic/bucket),
// then writes (src,dst) records grouped by bucket.
__global__ __launch_bounds__(256) void binpart_k(const int* __restrict__ src,
                                                 const int* __restrict__ dst,
                                                 int* __restrict__ bucket_cur,
                                                 uint2* __restrict__ binned,
                                                 int E, int NB) {
  __shared__ int hist[MAX_NB];
  int t = threadIdx.x;
  int e0 = blockIdx.x * BIN_CHUNK;
  int e1 = min(e0 + BIN_CHUNK, E);
  for (int b = t; b < NB; b += 256) hist[b] = 0;
  __syncthreads();
  for (int e = e0 + t; e < e1; e += 256) atomicAdd(&hist[dst[e] >> 8], 1);
  __syncthreads();
  for (int b = t; b < NB; b += 256) {
    int h = hist[b];
    hist[b] = h ? atomicAdd(&bucket_cur[b], h) : 0;
  }
  __syncthreads();
  for (int e = e0 + t; e < e1; e += 256) {
    int d = dst[e];
    int r = atomicAdd(&hist[d >> 8], 1);
    binned[r] = make_uint2((unsigned)src[e], (unsigned)d);
  }
}

// Pass 2: one block per bucket. Records are a coalesced stream; LDS cursors
// (seeded from rowoff) give final CSR positions; col writes stay in a ~32KB
// window per block -> full-line writebacks.
__global__ __launch_bounds__(256) void binscat_k(const uint2* __restrict__ binned,
                                                 const int* __restrict__ rowoff,
                                                 int* __restrict__ col, int N, int E) {
  __shared__ int lcur[256];
  int b = blockIdx.x, t = threadIdx.x;
  int node = (b << 8) + t;
  lcur[t] = (node < N) ? rowoff[node] : 0;
  int nb2 = (b + 1) << 8;
  int lo = rowoff[b << 8];
  int hi = (nb2 < N) ? rowoff[nb2] : E;
  __syncthreads();
  for (int e = lo + t; e < hi; e += 256) {
    uint2 rec = binned[e];
    int p = atomicAdd(&lcur[rec.y & 255], 1);
    col[p] = (int)rec.x;
  }
}

// g1 = bf16( dinv .* (x @ W1) ).  64 rows x 128 cols tile, K in 2x64 chunks.
__global__ __launch_bounds__(256) void gemm1_k(const float* __restrict__ x,
                                               const float* __restrict__ W,
                                               const float* __restrict__ dinv,
                                               unsigned* __restrict__ g1, int n) {
  __shared__ float Xs[64][68];
  __shared__ float Ws[64][132];
  int t = threadIdx.x;
  int row0 = blockIdx.x * 64;
  int cg = t & 15, rg = t >> 4;
  int c0 = cg * 8, r0 = rg * 4;

  float acc[4][8];
#pragma unroll
  for (int r = 0; r < 4; ++r)
#pragma unroll
    for (int c = 0; c < 8; ++c) acc[r][c] = 0.f;

  for (int ks = 0; ks < 2; ++ks) {
    __syncthreads();
#pragma unroll
    for (int q = 0; q < 4; ++q) {
      int f = t + q * 256;
      int r = f >> 4, c4 = f & 15;
      int grow = row0 + r;
      float4 v = make_float4(0.f, 0.f, 0.f, 0.f);
      if (grow < n) v = *(const float4*)(x + (size_t)grow * 128 + ks * 64 + c4 * 4);
      *(float4*)&Xs[r][c4 * 4] = v;
    }
#pragma unroll
    for (int q = 0; q < 8; ++q) {
      int f = t + q * 256;
      int k = f >> 5, c4 = f & 31;
      float4 v = *(const float4*)(W + (size_t)(ks * 64 + k) * 128 + c4 * 4);
      *(float4*)&Ws[k][c4 * 4] = v;
    }
    __syncthreads();

#pragma unroll
    for (int k4 = 0; k4 < 16; ++k4) {
      float4 xv0 = *(const float4*)&Xs[r0 + 0][k4 * 4];
      float4 xv1 = *(const float4*)&Xs[r0 + 1][k4 * 4];
      float4 xv2 = *(const float4*)&Xs[r0 + 2][k4 * 4];
      float4 xv3 = *(const float4*)&Xs[r0 + 3][k4 * 4];
#pragma unroll
      for (int kk = 0; kk < 4; ++kk) {
        const float* wrow = &Ws[k4 * 4 + kk][0];
        float4 wa = *(const float4*)(wrow + c0);
        float4 wb = *(const float4*)(wrow + c0 + 4);
        float a0 = kk == 0 ? xv0.x : kk == 1 ? xv0.y : kk == 2 ? xv0.z : xv0.w;
        float a1 = kk == 0 ? xv1.x : kk == 1 ? xv1.y : kk == 2 ? xv1.z : xv1.w;
        float a2 = kk == 0 ? xv2.x : kk == 1 ? xv2.y : kk == 2 ? xv2.z : xv2.w;
        float a3 = kk == 0 ? xv3.x : kk == 1 ? xv3.y : kk == 2 ? xv3.z : xv3.w;
        float as[4] = {a0, a1, a2, a3};
#pragma unroll
        for (int r = 0; r < 4; ++r) {
          acc[r][0] += as[r] * wa.x; acc[r][1] += as[r] * wa.y;
          acc[r][2] += as[r] * wa.z; acc[r][3] += as[r] * wa.w;
          acc[r][4] += as[r] * wb.x; acc[r][5] += as[r] * wb.y;
          acc[r][6] += as[r] * wb.z; acc[r][7] += as[r] * wb.w;
        }
      }
    }
  }

#pragma unroll
  for (int r = 0; r < 4; ++r) {
    int grow = row0 + r0 + r;
    if (grow < n) {
      float s = dinv[grow];
      uint4 pv;
      pv.x = bf16pack2(acc[r][0] * s, acc[r][1] * s);
      pv.y = bf16pack2(acc[r][2] * s, acc[r][3] * s);
      pv.z = bf16pack2(acc[r][4] * s, acc[r][5] * s);
      pv.w = bf16pack2(acc[r][6] * s, acc[r][7] * s);
      ((uint4*)g1)[(size_t)grow * 16 + cg] = pv;
    }
  }
}

// h1[i] = relu(dinv[i]*(sum_j g1[j] + g1[i]) + b1).  g1 is bf16 (128/row).
// One wave per node: 4 edge-parities x 16 lanes x 16B (8 bf16 ch each).
__global__ __launch_bounds__(256) void agg1_k(const unsigned* __restrict__ g1,
                                              const int* __restrict__ col,
                                              const int* __restrict__ rowoff,
                                              const int* __restrict__ counts,
                                              const float* __restrict__ dinv,
                                              const float* __restrict__ b1,
                                              float* __restrict__ h1, int n) {
  int w = threadIdx.x >> 6, lane = threadIdx.x & 63;
  int i = blockIdx.x * 4 + w;
  if (i >= n) return;
  int q = lane >> 4, c8 = lane & 15;  // channels c8*8 .. c8*8+7
  const uint4* g1v = (const uint4*)g1;  // 16 uint4 per row
  int start = rowoff[i], cnt = counts[i];

  float acc[8] = {0.f, 0.f, 0.f, 0.f, 0.f, 0.f, 0.f, 0.f};
  if (q == 0) acc_bf16x8(acc, g1v[(size_t)i * 16 + c8]);  // self-loop

#pragma unroll 4
  for (int e = q; e < cnt; e += 4) {
    int j = col[start + e];
    acc_bf16x8(acc, g1v[(size_t)j * 16 + c8]);
  }

#pragma unroll
  for (int k = 0; k < 8; ++k) {
    acc[k] += __shfl_xor(acc[k], 16, 64);
    acc[k] += __shfl_xor(acc[k], 32, 64);
  }

  if (q == 0) {
    float di = dinv[i];
    float4 ba = *(const float4*)(b1 + c8 * 8);
    float4 bb = *(const float4*)(b1 + c8 * 8 + 4);
    float4 o0, o1;
    o0.x = fmaxf(di * acc[0] + ba.x, 0.f);
    o0.y = fmaxf(di * acc[1] + ba.y, 0.f);
    o0.z = fmaxf(di * acc[2] + ba.z, 0.f);
    o0.w = fmaxf(di * acc[3] + ba.w, 0.f);
    o1.x = fmaxf(di * acc[4] + bb.x, 0.f);
    o1.y = fmaxf(di * acc[5] + bb.y, 0.f);
    o1.z = fmaxf(di * acc[6] + bb.z, 0.f);
    o1.w = fmaxf(di * acc[7] + bb.w, 0.f);
    float* o = h1 + (size_t)i * 128 + c8 * 8;
    *(float4*)o = o0;
    *(float4*)(o + 4) = o1;
  }
}

// g2 = bf16( dinv .* (h1 @ W2) ), padded to 64 cols (40..63 = 0).
__global__ __launch_bounds__(256) void gemm2_k(const float* __restrict__ h1,
                                               const float* __restrict__ W2,
                                               const float* __restrict__ dinv,
                                               unsigned* __restrict__ g2, int n) {
  __shared__ float Xs[64][68];
  __shared__ float Ws[64][68];
  int t = threadIdx.x;
  int row0 = blockIdx.x * 64;
  int cg = t & 7, rg = t >> 3;
  int c0 = cg * 8, r0 = rg * 2;

  float acc[2][8];
#pragma unroll
  for (int r = 0; r < 2; ++r)
#pragma unroll
    for (int c = 0; c < 8; ++c) acc[r][c] = 0.f;

  for (int idx = t; idx < 64 * 68; idx += 256) ((float*)Ws)[idx] = 0.f;

  for (int ks = 0; ks < 2; ++ks) {
    __syncthreads();
#pragma unroll
    for (int q = 0; q < 4; ++q) {
      int f = t + q * 256;
      int r = f >> 4, c4 = f & 15;
      int grow = row0 + r;
      float4 v = make_float4(0.f, 0.f, 0.f, 0.f);
      if (grow < n) v = *(const float4*)(h1 + (size_t)grow * 128 + ks * 64 + c4 * 4);
      *(float4*)&Xs[r][c4 * 4] = v;
    }
#pragma unroll
    for (int q = 0; q < 3; ++q) {
      int f = t + q * 256;
      if (f < 640) {
        int k = f / 10, c4 = f % 10;
        float4 v = *(const float4*)(W2 + (size_t)(ks * 64 + k) * 40 + c4 * 4);
        *(float4*)&Ws[k][c4 * 4] = v;
      }
    }
    __syncthreads();

#pragma unroll
    for (int k4 = 0; k4 < 16; ++k4) {
      float4 x0 = *(const float4*)&Xs[r0 + 0][k4 * 4];
      float4 x1 = *(const float4*)&Xs[r0 + 1][k4 * 4];
#pragma unroll
      for (int kk = 0; kk < 4; ++kk) {
        const float* wrow = &Ws[k4 * 4 + kk][0];
        float4 wa = *(const float4*)(wrow + c0);
        float4 wb = *(const float4*)(wrow + c0 + 4);
        float a0 = kk == 0 ? x0.x : kk == 1 ? x0.y : kk == 2 ? x0.z : x0.w;
        float a1 = kk == 0 ? x1.x : kk == 1 ? x1.y : kk == 2 ? x1.z : x1.w;
        acc[0][0] += a0 * wa.x; acc[0][1] += a0 * wa.y;
        acc[0][2] += a0 * wa.z; acc[0][3] += a0 * wa.w;
        acc[0][4] += a0 * wb.x; acc[0][5] += a0 * wb.y;
        acc[0][6] += a0 * wb.z; acc[0][7] += a0 * wb.w;
        acc[1][0] += a1 * wa.x; acc[1][1] += a1 * wa.y;
        acc[1][2] += a1 * wa.z; acc[1][3] += a1 * wa.w;
        acc[1][4] += a1 * wb.x; acc[1][5] += a1 * wb.y;
        acc[1][6] += a1 * wb.z; acc[1][7] += a1 * wb.w;
      }
    }
  }

#pragma unroll
  for (int r = 0; r < 2; ++r) {
    int grow = row0 + r0 + r;
    if (grow < n) {
      float s = dinv[grow];
      uint4 pv;
      pv.x = bf16pack2(acc[r][0] * s, acc[r][1] * s);
      pv.y = bf16pack2(acc[r][2] * s, acc[r][3] * s);
      pv.z = bf16pack2(acc[r][4] * s, acc[r][5] * s);
      pv.w = bf16pack2(acc[r][6] * s, acc[r][7] * s);
      ((uint4*)g2)[(size_t)grow * 8 + cg] = pv;
    }
  }
}

// out[i] = dinv[i]*(sum_j g2[j] + g2[i]) + b2.  g2 bf16, 64 ch padded.
__global__ __launch_bounds__(256) void agg2_k(const unsigned* __restrict__ g2,
                                              const int* __restrict__ col,
                                              const int* __restrict__ rowoff,
                                              const int* __restrict__ counts,
                                              const float* __restrict__ dinv,
                                              const float* __restrict__ b2,
                                              float* __restrict__ out, int n) {
  int w = threadIdx.x >> 6, lane = threadIdx.x & 63;
  int i = blockIdx.x * 4 + w;
  if (i >= n) return;
  int q = lane >> 3, c8 = lane & 7;
  const uint4* g2v = (const uint4*)g2;
  int start = rowoff[i], cnt = counts[i];

  float acc[8] = {0.f, 0.f, 0.f, 0.f, 0.f, 0.f, 0.f, 0.f};
  if (q == 0) acc_bf16x8(acc, g2v[(size_t)i * 8 + c8]);  // self-loop

#pragma unroll 4
  for (int e = q; e < cnt; e += 8) {
    int j = col[start + e];
    acc_bf16x8(acc, g2v[(size_t)j * 8 + c8]);
  }

#pragma unroll
  for (int k = 0; k < 8; ++k) {
    acc[k] += __shfl_xor(acc[k], 8, 64);
    acc[k] += __shfl_xor(acc[k], 16, 64);
    acc[k] += __shfl_xor(acc[k], 32, 64);
  }

  if (lane < 5) {
    float di = dinv[i];
    float4 ba = *(const float4*)(b2 + lane * 8);
    float4 bb = *(const float4*)(b2 + lane * 8 + 4);
    float4 o0, o1;
    o0.x = di * acc[0] + ba.x;
    o0.y = di * acc[1] + ba.y;
    o0.z = di * acc[2] + ba.z;
    o0.w = di * acc[3] + ba.w;
    o1.x = di * acc[4] + bb.x;
    o1.y = di * acc[5] + bb.y;
    o1.z = di * acc[6] + bb.z;
    o1.w = di * acc[7] + bb.w;
    float* o = out + (size_t)i * 40 + lane * 8;
    *(float4*)o = o0;
    *(float4*)(o + 4) = o1;
  }
}

extern "C" void kernel_launch(void* const* d_in, const int* in_sizes, int n_in,
                              void* d_out, int out_size, void* d_ws, size_t ws_size,
                              hipStream_t stream) {
  const float* x  = (const float*)d_in[0];
  const int*   ei = (const int*)d_in[1];
  const float* W1 = (const float*)d_in[2];
  const float* b1 = (const float*)d_in[3];
  const float* W2 = (const float*)d_in[4];
  const float* b2 = (const float*)d_in[5];
  float* out = (float*)d_out;

  const int N = in_sizes[0] / 128;
  const int E = in_sizes[1] / 2;
  const int* src = ei;
  const int* dst = ei + E;
  const int nblk = (N + 255) / 256;  // also == number of buckets NB

  size_t off = 0;
  auto alloc = [&](size_t bytes) {
    char* p = (char*)d_ws + off;
    off = align256(off + bytes);
    return (void*)p;
  };
  int*      counts = (int*)alloc((size_t)N * 4);
  int*      rowoff = (int*)alloc((size_t)N * 4);
  float*    dinv   = (float*)alloc((size_t)N * 4);
  int*      blksum = (int*)alloc((size_t)nblk * 4);
  int*      blkoff = (int*)alloc((size_t)nblk * 4);
  int*      bcur   = (int*)alloc((size_t)nblk * 4);
  int*      col    = (int*)alloc((size_t)E * 4);
  uint2*    binned = (uint2*)alloc((size_t)E * 8);
  unsigned* g1     = (unsigned*)alloc((size_t)N * 128 * 2);  // bf16; reused as g2
  float*    h1     = (float*)alloc((size_t)N * 128 * 4);
  unsigned* g2     = g1;  // g1 dead after agg1_k
  if (off > ws_size) return;
  if (nblk > MAX_NB) return;

  int gE = (E + 255) / 256;
  int gA = (N + 3) / 4;
  int gBin = (E + BIN_CHUNK - 1) / BIN_CHUNK;

  zero_k<<<(N + 255) / 256, 256, 0, stream>>>(counts, N);
  count_k<<<gE, 256, 0, stream>>>(dst, counts, E);
  scan1_k<<<nblk, 256, 0, stream>>>(counts, rowoff, blksum, dinv, N);
  scan2_k<<<1, 512, 0, stream>>>(blksum, blkoff, nblk);
  scan3_k<<<nblk, 256, 0, stream>>>(rowoff, blkoff, bcur, N);
  binpart_k<<<gBin, 256, 0, stream>>>(src, dst, bcur, binned, E, nblk);
  binscat_k<<<nblk, 256, 0, stream>>>(binned, rowoff, col, N, E);
  gemm1_k<<<(N + 63) / 64, 256, 0, stream>>>(x, W1, dinv, g1, N);
  agg1_k<<<gA, 256, 0, stream>>>(g1, col, rowoff, counts, dinv, b1, h1, N);
  gemm2_k<<<(N + 63) / 64, 256, 0, stream>>>(h1, W2, dinv, g2, N);
  agg2_k<<<gA, 256, 0, stream>>>(g2, col, rowoff, counts, dinv, b2, out, N);
}

// Round 5
// 505.650 us; speedup vs baseline: 2.6399x; 1.2032x over previous
//
#include <hip/hip_runtime.h>

// ---------------------------------------------------------------------------
// 2-layer GCN (PyG GCNConv semantics) on MI355X.
// out = dinv .* segsum(dinv .* (h @ W)) + b per layer, with self-loops.
// R5: CSR build fully bucketized — node-level counts/scan/scatter all happen
// inside per-bucket LDS windows (no global node-level atomics anywhere).
// g1/g2 stored bf16 (fp32 accumulation).
// ---------------------------------------------------------------------------

static inline size_t align256(size_t x) { return (x + 255) & ~(size_t)255; }

#define BIN_CHUNK 16384
#define MAX_NB 511  // buckets = ceil(N/256); N=100000 -> 391

__device__ __forceinline__ unsigned bf16pack2(float a, float b) {
  union { float f; unsigned u; } ua, ub;
  ua.f = a; ub.f = b;
  unsigned ra = (ua.u + 0x7fffu + ((ua.u >> 16) & 1u)) >> 16;
  unsigned rb = (ub.u + 0x7fffu + ((ub.u >> 16) & 1u)) >> 16;
  return ra | (rb << 16);
}

__device__ __forceinline__ void acc_bf16x8(float* acc, uint4 v) {
  union { unsigned u; float f; } c;
  c.u = v.x << 16;          acc[0] += c.f;
  c.u = v.x & 0xffff0000u;  acc[1] += c.f;
  c.u = v.y << 16;          acc[2] += c.f;
  c.u = v.y & 0xffff0000u;  acc[3] += c.f;
  c.u = v.z << 16;          acc[4] += c.f;
  c.u = v.z & 0xffff0000u;  acc[5] += c.f;
  c.u = v.w << 16;          acc[6] += c.f;
  c.u = v.w & 0xffff0000u;  acc[7] += c.f;
}

__global__ void zero_k(int* __restrict__ p, int n) {
  int i = blockIdx.x * blockDim.x + threadIdx.x;
  if (i < n) p[i] = 0;
}

// Per-chunk LDS bucket histogram -> one global atomic per (block,bucket).
__global__ __launch_bounds__(256) void bucket_count_k(const int* __restrict__ dst,
                                                      int* __restrict__ btot,
                                                      int E, int NB) {
  __shared__ int hist[MAX_NB];
  int t = threadIdx.x;
  for (int b = t; b < NB; b += 256) hist[b] = 0;
  __syncthreads();
  int e0 = blockIdx.x * BIN_CHUNK;
  int e1 = min(e0 + BIN_CHUNK, E);
  for (int e = e0 + t; e < e1; e += 256) atomicAdd(&hist[dst[e] >> 8], 1);
  __syncthreads();
  for (int b = t; b < NB; b += 256)
    if (hist[b]) atomicAdd(&btot[b], hist[b]);
}

// Single-block exclusive scan of bucket totals -> bucket_base[NB+1], bcur.
__global__ __launch_bounds__(512) void bucket_scan_k(const int* __restrict__ btot,
                                                     int* __restrict__ base,
                                                     int* __restrict__ bcur,
                                                     int NB, int E) {
  __shared__ int ws[8];
  int t = threadIdx.x, lane = t & 63, w = t >> 6;
  int v = (t < NB) ? btot[t] : 0;
  int incl = v;
#pragma unroll
  for (int off = 1; off < 64; off <<= 1) {
    int u = __shfl_up(incl, off, 64);
    if (lane >= off) incl += u;
  }
  if (lane == 63) ws[w] = incl;
  __syncthreads();
  int woff = 0;
  for (int k = 0; k < w; ++k) woff += ws[k];
  int excl = woff + incl - v;
  if (t < NB) { base[t] = excl; bcur[t] = excl; }
  if (t == 0) base[NB] = E;
}

// Reserve per-bucket segments (1 global atomic per block-bucket), write
// (src,dst) records grouped by bucket.
__global__ __launch_bounds__(256) void binpart_k(const int* __restrict__ src,
                                                 const int* __restrict__ dst,
                                                 int* __restrict__ bcur,
                                                 uint2* __restrict__ binned,
                                                 int E, int NB) {
  __shared__ int hist[MAX_NB];
  int t = threadIdx.x;
  int e0 = blockIdx.x * BIN_CHUNK;
  int e1 = min(e0 + BIN_CHUNK, E);
  for (int b = t; b < NB; b += 256) hist[b] = 0;
  __syncthreads();
  for (int e = e0 + t; e < e1; e += 256) atomicAdd(&hist[dst[e] >> 8], 1);
  __syncthreads();
  for (int b = t; b < NB; b += 256) {
    int h = hist[b];
    hist[b] = h ? atomicAdd(&bcur[b], h) : 0;
  }
  __syncthreads();
  for (int e = e0 + t; e < e1; e += 256) {
    int d = dst[e];
    int r = atomicAdd(&hist[d >> 8], 1);
    binned[r] = make_uint2((unsigned)src[e], (unsigned)d);
  }
}

// One block per bucket: LDS node-count, LDS scan -> counts/rowoff/dinv,
// then scatter col via LDS cursors. All global traffic is streaming.
__global__ __launch_bounds__(256) void binscat2_k(const uint2* __restrict__ binned,
                                                  const int* __restrict__ base,
                                                  int* __restrict__ counts,
                                                  int* __restrict__ rowoff,
                                                  float* __restrict__ dinv,
                                                  int* __restrict__ col, int N) {
  __shared__ int cnt[256];
  __shared__ int lcur[256];
  __shared__ int ws[4];
  int b = blockIdx.x, t = threadIdx.x;
  int lo = base[b], hi = base[b + 1];
  cnt[t] = 0;
  __syncthreads();
  for (int e = lo + t; e < hi; e += 256) atomicAdd(&cnt[binned[e].y & 255], 1);
  __syncthreads();
  int v = cnt[t];
  int lane = t & 63, w = t >> 6;
  int incl = v;
#pragma unroll
  for (int off = 1; off < 64; off <<= 1) {
    int u = __shfl_up(incl, off, 64);
    if (lane >= off) incl += u;
  }
  if (lane == 63) ws[w] = incl;
  __syncthreads();
  int woff = 0;
  for (int k = 0; k < w; ++k) woff += ws[k];
  int loff = woff + incl - v;  // exclusive within bucket
  int node = (b << 8) + t;
  if (node < N) {
    counts[node] = v;
    rowoff[node] = lo + loff;
    dinv[node] = rsqrtf((float)(v + 1));  // +1 self-loop
  }
  lcur[t] = lo + loff;
  __syncthreads();
  for (int e = lo + t; e < hi; e += 256) {
    uint2 rec = binned[e];
    int p = atomicAdd(&lcur[rec.y & 255], 1);
    col[p] = (int)rec.x;
  }
}

// g1 = bf16( dinv .* (x @ W1) ).  64 rows x 128 cols tile, K in 2x64 chunks.
__global__ __launch_bounds__(256) void gemm1_k(const float* __restrict__ x,
                                               const float* __restrict__ W,
                                               const float* __restrict__ dinv,
                                               unsigned* __restrict__ g1, int n) {
  __shared__ float Xs[64][68];
  __shared__ float Ws[64][132];
  int t = threadIdx.x;
  int row0 = blockIdx.x * 64;
  int cg = t & 15, rg = t >> 4;
  int c0 = cg * 8, r0 = rg * 4;

  float acc[4][8];
#pragma unroll
  for (int r = 0; r < 4; ++r)
#pragma unroll
    for (int c = 0; c < 8; ++c) acc[r][c] = 0.f;

  for (int ks = 0; ks < 2; ++ks) {
    __syncthreads();
#pragma unroll
    for (int q = 0; q < 4; ++q) {
      int f = t + q * 256;
      int r = f >> 4, c4 = f & 15;
      int grow = row0 + r;
      float4 v = make_float4(0.f, 0.f, 0.f, 0.f);
      if (grow < n) v = *(const float4*)(x + (size_t)grow * 128 + ks * 64 + c4 * 4);
      *(float4*)&Xs[r][c4 * 4] = v;
    }
#pragma unroll
    for (int q = 0; q < 8; ++q) {
      int f = t + q * 256;
      int k = f >> 5, c4 = f & 31;
      float4 v = *(const float4*)(W + (size_t)(ks * 64 + k) * 128 + c4 * 4);
      *(float4*)&Ws[k][c4 * 4] = v;
    }
    __syncthreads();

#pragma unroll
    for (int k4 = 0; k4 < 16; ++k4) {
      float4 xv0 = *(const float4*)&Xs[r0 + 0][k4 * 4];
      float4 xv1 = *(const float4*)&Xs[r0 + 1][k4 * 4];
      float4 xv2 = *(const float4*)&Xs[r0 + 2][k4 * 4];
      float4 xv3 = *(const float4*)&Xs[r0 + 3][k4 * 4];
#pragma unroll
      for (int kk = 0; kk < 4; ++kk) {
        const float* wrow = &Ws[k4 * 4 + kk][0];
        float4 wa = *(const float4*)(wrow + c0);
        float4 wb = *(const float4*)(wrow + c0 + 4);
        float a0 = kk == 0 ? xv0.x : kk == 1 ? xv0.y : kk == 2 ? xv0.z : xv0.w;
        float a1 = kk == 0 ? xv1.x : kk == 1 ? xv1.y : kk == 2 ? xv1.z : xv1.w;
        float a2 = kk == 0 ? xv2.x : kk == 1 ? xv2.y : kk == 2 ? xv2.z : xv2.w;
        float a3 = kk == 0 ? xv3.x : kk == 1 ? xv3.y : kk == 2 ? xv3.z : xv3.w;
        float as[4] = {a0, a1, a2, a3};
#pragma unroll
        for (int r = 0; r < 4; ++r) {
          acc[r][0] += as[r] * wa.x; acc[r][1] += as[r] * wa.y;
          acc[r][2] += as[r] * wa.z; acc[r][3] += as[r] * wa.w;
          acc[r][4] += as[r] * wb.x; acc[r][5] += as[r] * wb.y;
          acc[r][6] += as[r] * wb.z; acc[r][7] += as[r] * wb.w;
        }
      }
    }
  }

#pragma unroll
  for (int r = 0; r < 4; ++r) {
    int grow = row0 + r0 + r;
    if (grow < n) {
      float s = dinv[grow];
      uint4 pv;
      pv.x = bf16pack2(acc[r][0] * s, acc[r][1] * s);
      pv.y = bf16pack2(acc[r][2] * s, acc[r][3] * s);
      pv.z = bf16pack2(acc[r][4] * s, acc[r][5] * s);
      pv.w = bf16pack2(acc[r][6] * s, acc[r][7] * s);
      ((uint4*)g1)[(size_t)grow * 16 + cg] = pv;
    }
  }
}

// h1[i] = relu(dinv[i]*(sum_j g1[j] + g1[i]) + b1).  g1 is bf16 (128/row).
// One wave per node: 4 edge-parities x 16 lanes x 16B (8 bf16 ch each).
__global__ __launch_bounds__(256) void agg1_k(const unsigned* __restrict__ g1,
                                              const int* __restrict__ col,
                                              const int* __restrict__ rowoff,
                                              const int* __restrict__ counts,
                                              const float* __restrict__ dinv,
                                              const float* __restrict__ b1,
                                              float* __restrict__ h1, int n) {
  int w = threadIdx.x >> 6, lane = threadIdx.x & 63;
  int i = blockIdx.x * 4 + w;
  if (i >= n) return;
  int q = lane >> 4, c8 = lane & 15;
  const uint4* g1v = (const uint4*)g1;
  int start = rowoff[i], cnt = counts[i];

  float acc[8] = {0.f, 0.f, 0.f, 0.f, 0.f, 0.f, 0.f, 0.f};
  if (q == 0) acc_bf16x8(acc, g1v[(size_t)i * 16 + c8]);  // self-loop

#pragma unroll 4
  for (int e = q; e < cnt; e += 4) {
    int j = col[start + e];
    acc_bf16x8(acc, g1v[(size_t)j * 16 + c8]);
  }

#pragma unroll
  for (int k = 0; k < 8; ++k) {
    acc[k] += __shfl_xor(acc[k], 16, 64);
    acc[k] += __shfl_xor(acc[k], 32, 64);
  }

  if (q == 0) {
    float di = dinv[i];
    float4 ba = *(const float4*)(b1 + c8 * 8);
    float4 bb = *(const float4*)(b1 + c8 * 8 + 4);
    float4 o0, o1;
    o0.x = fmaxf(di * acc[0] + ba.x, 0.f);
    o0.y = fmaxf(di * acc[1] + ba.y, 0.f);
    o0.z = fmaxf(di * acc[2] + ba.z, 0.f);
    o0.w = fmaxf(di * acc[3] + ba.w, 0.f);
    o1.x = fmaxf(di * acc[4] + bb.x, 0.f);
    o1.y = fmaxf(di * acc[5] + bb.y, 0.f);
    o1.z = fmaxf(di * acc[6] + bb.z, 0.f);
    o1.w = fmaxf(di * acc[7] + bb.w, 0.f);
    float* o = h1 + (size_t)i * 128 + c8 * 8;
    *(float4*)o = o0;
    *(float4*)(o + 4) = o1;
  }
}

// g2 = bf16( dinv .* (h1 @ W2) ), padded to 64 cols (40..63 = 0).
__global__ __launch_bounds__(256) void gemm2_k(const float* __restrict__ h1,
                                               const float* __restrict__ W2,
                                               const float* __restrict__ dinv,
                                               unsigned* __restrict__ g2, int n) {
  __shared__ float Xs[64][68];
  __shared__ float Ws[64][68];
  int t = threadIdx.x;
  int row0 = blockIdx.x * 64;
  int cg = t & 7, rg = t >> 3;
  int c0 = cg * 8, r0 = rg * 2;

  float acc[2][8];
#pragma unroll
  for (int r = 0; r < 2; ++r)
#pragma unroll
    for (int c = 0; c < 8; ++c) acc[r][c] = 0.f;

  for (int idx = t; idx < 64 * 68; idx += 256) ((float*)Ws)[idx] = 0.f;

  for (int ks = 0; ks < 2; ++ks) {
    __syncthreads();
#pragma unroll
    for (int q = 0; q < 4; ++q) {
      int f = t + q * 256;
      int r = f >> 4, c4 = f & 15;
      int grow = row0 + r;
      float4 v = make_float4(0.f, 0.f, 0.f, 0.f);
      if (grow < n) v = *(const float4*)(h1 + (size_t)grow * 128 + ks * 64 + c4 * 4);
      *(float4*)&Xs[r][c4 * 4] = v;
    }
#pragma unroll
    for (int q = 0; q < 3; ++q) {
      int f = t + q * 256;
      if (f < 640) {
        int k = f / 10, c4 = f % 10;
        float4 v = *(const float4*)(W2 + (size_t)(ks * 64 + k) * 40 + c4 * 4);
        *(float4*)&Ws[k][c4 * 4] = v;
      }
    }
    __syncthreads();

#pragma unroll
    for (int k4 = 0; k4 < 16; ++k4) {
      float4 x0 = *(const float4*)&Xs[r0 + 0][k4 * 4];
      float4 x1 = *(const float4*)&Xs[r0 + 1][k4 * 4];
#pragma unroll
      for (int kk = 0; kk < 4; ++kk) {
        const float* wrow = &Ws[k4 * 4 + kk][0];
        float4 wa = *(const float4*)(wrow + c0);
        float4 wb = *(const float4*)(wrow + c0 + 4);
        float a0 = kk == 0 ? x0.x : kk == 1 ? x0.y : kk == 2 ? x0.z : x0.w;
        float a1 = kk == 0 ? x1.x : kk == 1 ? x1.y : kk == 2 ? x1.z : x1.w;
        acc[0][0] += a0 * wa.x; acc[0][1] += a0 * wa.y;
        acc[0][2] += a0 * wa.z; acc[0][3] += a0 * wa.w;
        acc[0][4] += a0 * wb.x; acc[0][5] += a0 * wb.y;
        acc[0][6] += a0 * wb.z; acc[0][7] += a0 * wb.w;
        acc[1][0] += a1 * wa.x; acc[1][1] += a1 * wa.y;
        acc[1][2] += a1 * wa.z; acc[1][3] += a1 * wa.w;
        acc[1][4] += a1 * wb.x; acc[1][5] += a1 * wb.y;
        acc[1][6] += a1 * wb.z; acc[1][7] += a1 * wb.w;
      }
    }
  }

#pragma unroll
  for (int r = 0; r < 2; ++r) {
    int grow = row0 + r0 + r;
    if (grow < n) {
      float s = dinv[grow];
      uint4 pv;
      pv.x = bf16pack2(acc[r][0] * s, acc[r][1] * s);
      pv.y = bf16pack2(acc[r][2] * s, acc[r][3] * s);
      pv.z = bf16pack2(acc[r][4] * s, acc[r][5] * s);
      pv.w = bf16pack2(acc[r][6] * s, acc[r][7] * s);
      ((uint4*)g2)[(size_t)grow * 8 + cg] = pv;
    }
  }
}

// out[i] = dinv[i]*(sum_j g2[j] + g2[i]) + b2.  g2 bf16, 64 ch padded.
// One wave per node: 8 edge-parities x 8 lanes x 16B (8 bf16 ch each).
__global__ __launch_bounds__(256) void agg2_k(const unsigned* __restrict__ g2,
                                              const int* __restrict__ col,
                                              const int* __restrict__ rowoff,
                                              const int* __restrict__ counts,
                                              const float* __restrict__ dinv,
                                              const float* __restrict__ b2,
                                              float* __restrict__ out, int n) {
  int w = threadIdx.x >> 6, lane = threadIdx.x & 63;
  int i = blockIdx.x * 4 + w;
  if (i >= n) return;
  int q = lane >> 3, c8 = lane & 7;
  const uint4* g2v = (const uint4*)g2;
  int start = rowoff[i], cnt = counts[i];

  float acc[8] = {0.f, 0.f, 0.f, 0.f, 0.f, 0.f, 0.f, 0.f};
  if (q == 0) acc_bf16x8(acc, g2v[(size_t)i * 8 + c8]);  // self-loop

#pragma unroll 4
  for (int e = q; e < cnt; e += 8) {
    int j = col[start + e];
    acc_bf16x8(acc, g2v[(size_t)j * 8 + c8]);
  }

#pragma unroll
  for (int k = 0; k < 8; ++k) {
    acc[k] += __shfl_xor(acc[k], 8, 64);
    acc[k] += __shfl_xor(acc[k], 16, 64);
    acc[k] += __shfl_xor(acc[k], 32, 64);
  }

  if (lane < 5) {
    float di = dinv[i];
    float4 ba = *(const float4*)(b2 + lane * 8);
    float4 bb = *(const float4*)(b2 + lane * 8 + 4);
    float4 o0, o1;
    o0.x = di * acc[0] + ba.x;
    o0.y = di * acc[1] + ba.y;
    o0.z = di * acc[2] + ba.z;
    o0.w = di * acc[3] + ba.w;
    o1.x = di * acc[4] + bb.x;
    o1.y = di * acc[5] + bb.y;
    o1.z = di * acc[6] + bb.z;
    o1.w = di * acc[7] + bb.w;
    float* o = out + (size_t)i * 40 + lane * 8;
    *(float4*)o = o0;
    *(float4*)(o + 4) = o1;
  }
}

extern "C" void kernel_launch(void* const* d_in, const int* in_sizes, int n_in,
                              void* d_out, int out_size, void* d_ws, size_t ws_size,
                              hipStream_t stream) {
  const float* x  = (const float*)d_in[0];
  const int*   ei = (const int*)d_in[1];
  const float* W1 = (const float*)d_in[2];
  const float* b1 = (const float*)d_in[3];
  const float* W2 = (const float*)d_in[4];
  const float* b2 = (const float*)d_in[5];
  float* out = (float*)d_out;

  const int N = in_sizes[0] / 128;
  const int E = in_sizes[1] / 2;
  const int* src = ei;
  const int* dst = ei + E;
  const int NB = (N + 255) / 256;  // buckets

  size_t off = 0;
  auto alloc = [&](size_t bytes) {
    char* p = (char*)d_ws + off;
    off = align256(off + bytes);
    return (void*)p;
  };
  int*      counts = (int*)alloc((size_t)N * 4);
  int*      rowoff = (int*)alloc((size_t)N * 4);
  float*    dinv   = (float*)alloc((size_t)N * 4);
  int*      btot   = (int*)alloc((size_t)NB * 4);
  int*      base   = (int*)alloc((size_t)(NB + 1) * 4);
  int*      bcur   = (int*)alloc((size_t)NB * 4);
  int*      col    = (int*)alloc((size_t)E * 4);
  uint2*    binned = (uint2*)alloc((size_t)E * 8);
  unsigned* g1     = (unsigned*)alloc((size_t)N * 128 * 2);  // bf16; reused as g2
  float*    h1     = (float*)alloc((size_t)N * 128 * 4);
  unsigned* g2     = g1;  // g1 dead after agg1_k
  if (off > ws_size) return;
  if (NB > MAX_NB) return;

  int gA = (N + 3) / 4;
  int gBin = (E + BIN_CHUNK - 1) / BIN_CHUNK;

  zero_k<<<(NB + 255) / 256, 256, 0, stream>>>(btot, NB);
  bucket_count_k<<<gBin, 256, 0, stream>>>(dst, btot, E, NB);
  bucket_scan_k<<<1, 512, 0, stream>>>(btot, base, bcur, NB, E);
  binpart_k<<<gBin, 256, 0, stream>>>(src, dst, bcur, binned, E, NB);
  binscat2_k<<<NB, 256, 0, stream>>>(binned, base, counts, rowoff, dinv, col, N);
  gemm1_k<<<(N + 63) / 64, 256, 0, stream>>>(x, W1, dinv, g1, N);
  agg1_k<<<gA, 256, 0, stream>>>(g1, col, rowoff, counts, dinv, b1, h1, N);
  gemm2_k<<<(N + 63) / 64, 256, 0, stream>>>(h1, W2, dinv, g2, N);
  agg2_k<<<gA, 256, 0, stream>>>(g2, col, rowoff, counts, dinv, b2, out, N);
}